// Round 20
// baseline (26.812 us; speedup 1.0000x reference)
//
#include <hip/hip_runtime.h>
#include <math.h>

#define NPTS 4096
#define NB   8
#define QG   512          // queries per block: 4 waves x T x 32
#define RCC  512          // refs per block chunk
#define NQG  (NPTS / QG)  // 8
#define NRC  (NPTS / RCC) // 8
#define T    4

typedef _Float16 h8     __attribute__((ext_vector_type(8)));
typedef float    f32x16 __attribute__((ext_vector_type(16)));

#define FOREACH_T(OP) OP(0) OP(1) OP(2) OP(3)

__device__ __forceinline__ void split2(float v, _Float16& h, _Float16& l) {
    h = (_Float16)v;
    l = (_Float16)(v - (float)h);
}

// k0: precompute MFMA operand fragments for every entity (R9-validated
// hi/lo-split K=16 embedding, exact). A-form embeds [-2x,-2y,-2z,n,1],
// B-form embeds [x,y,z,1,n]; sum_k A_k B_k = |p|^2+|g|^2-2p.g.
// Layout: F*[b][kg][NPTS] (16B entries).
__global__ __launch_bounds__(1024) void chamfer_frags(
    const float* __restrict__ P, const float* __restrict__ G,
    h8* __restrict__ FA_P, h8* __restrict__ FB_P,
    h8* __restrict__ FA_G, h8* __restrict__ FB_G, int* __restrict__ counter)
{
    const int g = blockIdx.x * 1024 + threadIdx.x;   // 65536 = 2 sets x 8 b x 4096
    if (g == 0) *counter = 0;
    const int set = g >> 15;
    const int b   = (g >> 12) & 7;
    const int i   = g & 4095;
    const float* src = (set ? G : P) + ((size_t)b * NPTS + i) * 3;
    const float x = src[0], y = src[1], z = src[2];
    const float n = fmaf(x, x, fmaf(y, y, z * z));
    const float m2x = -2.f * x, m2y = -2.f * y, m2z = -2.f * z;
    const _Float16 one = (_Float16)1.f, zr = (_Float16)0.f;
    _Float16 axh, axl, ayh, ayl, azh, azl, anh, anl;   // A-form: -2*coord, n
    split2(m2x, axh, axl); split2(m2y, ayh, ayl); split2(m2z, azh, azl);
    split2(n, anh, anl);
    _Float16 bxh, bxl, byh, byl, bzh, bzl;             // B-form: raw coord, n
    split2(x, bxh, bxl); split2(y, byh, byl); split2(z, bzh, bzl);

    h8* FA = (set ? FA_G : FA_P) + (size_t)b * 2 * NPTS;
    h8* FB = (set ? FB_G : FB_P) + (size_t)b * 2 * NPTS;
    FA[i]        = (h8){axh, ayh, azh, anh, one, axl, ayl, azl};
    FA[NPTS + i] = (h8){anl, zr, axh, ayh, azh, anh, one, zr};
    FB[i]        = (h8){bxh, byh, bzh, one, anh, bxh, byh, bzh};
    FB[NPTS + i] = (h8){one, anh, bxl, byl, bzl, zr, anl, zr};
}

// k1: two passes (grid.z): pass0 A=gts,B=points -> p2g; pass1 A=points,B=gts.
// MFMA rows = A (register-indexed) = the min axis -> pure per-lane min3 tree;
// cols = B (lane) = queries. NO cross-lane reduction, NO transpose, NO atomics.
// Inner step: 1 ds_read_b128 + T=4 MFMA + 4 x 8-op tree.
__global__ __launch_bounds__(256, 4) void chamfer_mfma32(
    const h8* __restrict__ FA_P, const h8* __restrict__ FB_P,
    const h8* __restrict__ FA_G, const h8* __restrict__ FB_G,
    float* __restrict__ part)   // [2][NB][16][NPTS]; chunk = rc*2+kg
{
    __shared__ h8 Alds[2][RCC];   // 16 KB, [kg][entity]

    const int pass = blockIdx.z;
    const int b    = blockIdx.y;
    const int qg   = blockIdx.x >> 3;  // 0..7
    const int rc   = blockIdx.x & 7;   // 0..7
    const int tid  = threadIdx.x;
    const int w    = tid >> 6;
    const int lane = tid & 63;
    const int col  = lane & 31;
    const int kg   = lane >> 5;

    const h8* __restrict__ FA = (pass ? FA_P : FA_G) + (size_t)b * 2 * NPTS;
    const h8* __restrict__ FB = (pass ? FB_G : FB_P) + (size_t)b * 2 * NPTS;

    // stage this chunk's A-fragments (1024 entries, contiguous b128 copies)
#pragma unroll
    for (int i = 0; i < 4; ++i) {
        const int e   = tid + i * 256;
        const int ekg = e >> 9, le = e & 511;
        Alds[ekg][le] = FA[(size_t)ekg * NPTS + rc * RCC + le];
    }

    // B-fragments (queries) constant in registers; acc per query
    const int qb = qg * QG + w * (T * 32);
#define DECLT(t) h8 bf##t; float acc##t;
    FOREACH_T(DECLT)
#undef DECLT
#define LOADB(t) bf##t = FB[(size_t)kg * NPTS + qb + (t) * 32 + col]; acc##t = 3.4e38f;
    FOREACH_T(LOADB)
#undef LOADB

    __syncthreads();

    const f32x16 cz = (f32x16){0.f,0.f,0.f,0.f,0.f,0.f,0.f,0.f,
                               0.f,0.f,0.f,0.f,0.f,0.f,0.f,0.f};
#pragma unroll 4
    for (int rt = 0; rt < RCC / 32; ++rt) {
        const h8 a = Alds[kg][rt * 32 + col];
#define DOT(t) { \
        f32x16 d = __builtin_amdgcn_mfma_f32_32x32x16_f16(a, bf##t, cz, 0, 0, 0); \
        float t0 = fminf(fminf(d[0],  d[1]),  d[2]);                          \
        float t1 = fminf(fminf(d[3],  d[4]),  d[5]);                          \
        float t2 = fminf(fminf(d[6],  d[7]),  d[8]);                          \
        float t3 = fminf(fminf(d[9],  d[10]), d[11]);                         \
        float t4 = fminf(fminf(d[12], d[13]), d[14]);                         \
        float u0 = fminf(fminf(t0, t1), t2);                                  \
        float u1 = fminf(fminf(t3, t4), d[15]);                               \
        acc##t = fminf(fminf(u0, u1), acc##t); }
        FOREACH_T(DOT)
#undef DOT
    }

    // epilogue: 4 coalesced stores; kg halves own separate chunk slots
    float* outb = part + (((size_t)(pass * NB + b)) * 16 + rc * 2 + kg) * NPTS + qb;
#define STORET(t) outb[(t) * 32 + col] = fmaxf(acc##t, 0.f);
    FOREACH_T(STORET)
#undef STORET
}

// k2: 64 blocks (path, b, sp); min over the 16 chunk partials per element,
// sum 1024 -> sums[64]; last block: 16 x sqrt(mean) -> 3 outputs. (R18-proven.)
__global__ __launch_bounds__(256) void chamfer_reduce2(
    const float* __restrict__ part,
    float* __restrict__ sums, int* __restrict__ counter, float* __restrict__ out)
{
    const int t  = blockIdx.x >> 2;      // 0..15 = pass*8 + b
    const int sp = blockIdx.x & 3;
    const float* __restrict__ base = part + (size_t)t * 16 * NPTS;

    float sum = 0.f;
#pragma unroll
    for (int i = 0; i < 4; ++i) {
        const int q = sp * 1024 + i * 256 + threadIdx.x;
        float mn = base[q];
#pragma unroll
        for (int c = 1; c < 16; ++c) mn = fminf(mn, base[(size_t)c * NPTS + q]);
        sum += fmaxf(mn, 0.f);
    }

    __shared__ float red[256];
    __shared__ int amLast;
    red[threadIdx.x] = sum;
    __syncthreads();
    if (threadIdx.x < 128) red[threadIdx.x] += red[threadIdx.x + 128];
    __syncthreads();
    if (threadIdx.x < 64) {
        float v = red[threadIdx.x] + red[threadIdx.x + 64];
#pragma unroll
        for (int off = 32; off > 0; off >>= 1) v += __shfl_down(v, off, 64);
        if (threadIdx.x == 0) {
            sums[blockIdx.x] = v;
            __threadfence();
            amLast = (atomicAdd(counter, 1) == 63);
        }
    }
    __syncthreads();

    if (amLast) {
        __shared__ float r16[16];
        if (threadIdx.x < 16) {
            float acc = 0.f;
#pragma unroll
            for (int k = 0; k < 4; ++k)
                acc += *(volatile const float*)&sums[threadIdx.x * 4 + k];
            r16[threadIdx.x] = sqrtf(acc / (float)NPTS);
        }
        __syncthreads();
        if (threadIdx.x == 0) {
            float p2g = 0.f, g2p = 0.f;
#pragma unroll
            for (int bb = 0; bb < NB; ++bb) { p2g += r16[bb]; g2p += r16[NB + bb]; }
            p2g *= (1.0f / NB);
            g2p *= (1.0f / NB);
            out[0] = 0.5f * (p2g + g2p);
            out[1] = p2g;
            out[2] = g2p;
            *counter = 0;   // clean for next replay
        }
    }
}

extern "C" void kernel_launch(void* const* d_in, const int* in_sizes, int n_in,
                              void* d_out, int out_size, void* d_ws, size_t ws_size,
                              hipStream_t stream) {
    const float* points = (const float*)d_in[0];
    const float* gts    = (const float*)d_in[1];
    float* out = (float*)d_out;

    const size_t FRAG = (size_t)NB * 2 * NPTS;            // 65536 entries
    h8* FA_P = (h8*)d_ws;
    h8* FB_P = FA_P + FRAG;
    h8* FA_G = FB_P + FRAG;
    h8* FB_G = FA_G + FRAG;                               // 4 x 1 MB
    float* part = (float*)(FB_G + FRAG);                  // [2][8][16][4096] = 4 MB
    float* sums = part + (size_t)2 * NB * 16 * NPTS;      // 64 floats
    int*   counter = (int*)(sums + 64);

    chamfer_frags<<<dim3(64), 1024, 0, stream>>>(points, gts,
                                                 FA_P, FB_P, FA_G, FB_G, counter);

    dim3 grid1(NQG * NRC, NB, 2);   // 64 x 8 x 2 = 1024 blocks, 256 thr, 4/CU
    chamfer_mfma32<<<grid1, 256, 0, stream>>>(FA_P, FB_P, FA_G, FB_G, part);

    chamfer_reduce2<<<dim3(64), 256, 0, stream>>>(part, sums, counter, out);
}